// Round 6
// baseline (633.494 us; speedup 1.0000x reference)
//
#include <hip/hip_runtime.h>

#define NND 50000
#define NED 800000
#define NF  128
#define NH  64
#define BN_EPS 1e-5

// ---- workspace byte offsets (all 16B aligned) ----
#define WS_HA     0                         // float[NND*64]      12,800,000 B
#define WS_STATS  12800000                  // double[4][128]      4,096 B (sum, sumsq per stage)
#define WS_SS     (WS_STATS + 4*128*8)      // (unused now)
#define WS_DEG    (WS_SS + 4*128*4)         // int[NND]
#define WS_OFFS   (WS_DEG + NND*4)          // int[NND+4]
#define WS_CUR    (WS_OFFS + (NND+4)*4)     // int[NND]
#define WS_ESRC   (WS_CUR + NND*4)          // int[NED]

// ---------------- CSR build ----------------
__global__ void k_deg(const int* __restrict__ dst, int* __restrict__ deg) {
    int e = blockIdx.x * 256 + threadIdx.x;
    if (e < NED) atomicAdd(&deg[dst[e]], 1);
}

__global__ __launch_bounds__(1024) void k_scan(const int* __restrict__ deg,
                                               int* __restrict__ offs) {
    __shared__ int sd[1024];
    int t = threadIdx.x;
    const int C = (NND + 1023) / 1024;   // 49
    int s = t * C; if (s > NND) s = NND;
    int e = s + C; if (e > NND) e = NND;
    int loc = 0;
    for (int i = s; i < e; ++i) loc += deg[i];
    sd[t] = loc;
    __syncthreads();
    for (int off = 1; off < 1024; off <<= 1) {
        int v = (t >= off) ? sd[t - off] : 0;
        __syncthreads();
        sd[t] += v;
        __syncthreads();
    }
    int run = sd[t] - loc;   // exclusive prefix
    for (int i = s; i < e; ++i) { offs[i] = run; run += deg[i]; }
    if (t == 1023) offs[NND] = sd[1023];
}

__global__ void k_fill(const int* __restrict__ src, const int* __restrict__ dst,
                       int* __restrict__ cur, int* __restrict__ esrc) {
    int e = blockIdx.x * 256 + threadIdx.x;
    if (e < NED) {
        int d = dst[e];
        int pos = atomicAdd(&cur[d], 1);
        esrc[pos] = src[e];
    }
}

// ---------------- input transform: h0 = x @ W_t + b_t (raw) + stats ----------------
// Chunked-K (4 x 32) double-buffered pipeline: issue next chunk's loads BEFORE
// compute (T14 split) so HBM latency hides under the FMA loop.
__global__ __launch_bounds__(256) void k_transform(const float* __restrict__ x,
                                                   const float* __restrict__ Wt,
                                                   const float* __restrict__ bt,
                                                   float* __restrict__ outraw,
                                                   double* __restrict__ stats) {
    __shared__ float Wl[NF * NH];      // 32 KB
    __shared__ float sA[2][32 * 68];   // 2 x 8.5 KB, [k-local][node] pad-68
    int tid = threadIdx.x;
    int kk = tid & 31, nw = tid >> 5;       // staging: k-lane (32), node-group (8)
    int tn = tid & 15, tc = tid >> 4;       // GEMM: 4 nodes x 4 cols per thread
    int base = blockIdx.x * 64;

    // prologue: issue all W loads + chunk-0 loads, then write
    float4 wld[8];
#pragma unroll
    for (int r = 0; r < 8; ++r) wld[r] = ((const float4*)Wt)[r * 256 + tid];
    float nx[8];
#pragma unroll
    for (int s = 0; s < 8; ++s) {
        int n = s * 8 + nw;
        nx[s] = (base + n < NND) ? x[(size_t)(base + n) * NF + kk] : 0.f;
    }
#pragma unroll
    for (int r = 0; r < 8; ++r) ((float4*)Wl)[r * 256 + tid] = wld[r];
#pragma unroll
    for (int s = 0; s < 8; ++s) sA[0][kk * 68 + s * 8 + nw] = nx[s];
    __syncthreads();

    float acc[4][4];
#pragma unroll
    for (int i = 0; i < 4; ++i)
#pragma unroll
        for (int j = 0; j < 4; ++j) acc[i][j] = 0.f;

#pragma unroll
    for (int c = 0; c < 4; ++c) {
        float pf[8];
        if (c < 3) {
#pragma unroll
            for (int s = 0; s < 8; ++s) {
                int n = s * 8 + nw;
                pf[s] = (base + n < NND)
                      ? x[(size_t)(base + n) * NF + (c + 1) * 32 + kk] : 0.f;
            }
        }
        const float* Ab = sA[c & 1];
#pragma unroll 8
        for (int kl = 0; kl < 32; ++kl) {
            float4 a  = *(const float4*)&Ab[kl * 68 + tn * 4];
            float4 wv = *(const float4*)&Wl[(c * 32 + kl) * NH + tc * 4];
            float av[4]  = {a.x, a.y, a.z, a.w};
            float wvv[4] = {wv.x, wv.y, wv.z, wv.w};
#pragma unroll
            for (int i = 0; i < 4; ++i)
#pragma unroll
                for (int j = 0; j < 4; ++j) acc[i][j] += av[i] * wvv[j];
        }
        if (c < 3) {
#pragma unroll
            for (int s = 0; s < 8; ++s) sA[(c + 1) & 1][kk * 68 + s * 8 + nw] = pf[s];
        }
        __syncthreads();
    }

    float4 bv = ((const float4*)bt)[tc];
    float bj[4] = {bv.x, bv.y, bv.z, bv.w};

    double sum[4] = {0, 0, 0, 0}, ssq[4] = {0, 0, 0, 0};
#pragma unroll
    for (int i = 0; i < 4; ++i) {
        int n = base + tn * 4 + i;
        if (n < NND) {
            float o0 = acc[i][0] + bj[0], o1 = acc[i][1] + bj[1];
            float o2 = acc[i][2] + bj[2], o3 = acc[i][3] + bj[3];
            float4 o = {o0, o1, o2, o3};
            *(float4*)&outraw[(size_t)n * NH + tc * 4] = o;
            sum[0] += o0; ssq[0] += (double)o0 * o0;
            sum[1] += o1; ssq[1] += (double)o1 * o1;
            sum[2] += o2; ssq[2] += (double)o2 * o2;
            sum[3] += o3; ssq[3] += (double)o3 * o3;
        }
    }
#pragma unroll
    for (int m = 1; m < 16; m <<= 1) {
#pragma unroll
        for (int j = 0; j < 4; ++j) {
            sum[j] += __shfl_xor(sum[j], m);
            ssq[j] += __shfl_xor(ssq[j], m);
        }
    }
    if (tn == 0) {
#pragma unroll
        for (int j = 0; j < 4; ++j) {
            atomicAdd(&stats[tc * 4 + j], sum[j]);
            atomicAdd(&stats[64 + tc * 4 + j], ssq[j]);
        }
    }
}

// ---------------- aggregation: wave-per-node, float4 gather (4 edges/instr) ----------------
// out[n][c] = sc[c]*( raw[n][c] + sum_{j->n} raw[j][c] ) + (deg+1)*sh[c]
// BN finalize folded in (sc/sh computed from stats in-kernel).
__global__ __launch_bounds__(256) void k_agg(const float* __restrict__ inraw,
                                             float* __restrict__ aggout,
                                             const double* __restrict__ st,
                                             const float* __restrict__ g,
                                             const float* __restrict__ b,
                                             const int* __restrict__ offs,
                                             const int* __restrict__ esrc) {
    int tid  = threadIdx.x;
    int lane = tid & 63;
    int wv   = tid >> 6;
    int n = blockIdx.x * 4 + wv;           // 12500 blocks x 4 waves = 50000 nodes
    int q = lane & 15;                     // col quad (cols q*4 .. q*4+3)
    int r = lane >> 4;                     // edge slot 0..3
    const float4* in4 = (const float4*)inraw;

    int e0 = offs[n], e1 = offs[n + 1];
    int deg = e1 - e0;

    float4 self = make_float4(0.f, 0.f, 0.f, 0.f);
    if (r == 0) self = in4[(size_t)n * 16 + q];   // issued early, latency hidden

    float ax = 0.f, ay = 0.f, az = 0.f, aw = 0.f;
    for (int bb = e0; bb < e1; bb += 64) {
        int m = e1 - bb; if (m > 64) m = 64;
        int idx = (lane < m) ? esrc[bb + lane] : 0;   // one coalesced index load / 64 edges
        int t = 0;
        for (; t + 16 <= m; t += 16) {                // 16 edges in flight
            int j0 = __shfl(idx, t + r);
            int j1 = __shfl(idx, t + 4 + r);
            int j2 = __shfl(idx, t + 8 + r);
            int j3 = __shfl(idx, t + 12 + r);
            float4 v0 = in4[(size_t)j0 * 16 + q];
            float4 v1 = in4[(size_t)j1 * 16 + q];
            float4 v2 = in4[(size_t)j2 * 16 + q];
            float4 v3 = in4[(size_t)j3 * 16 + q];
            ax += (v0.x + v1.x) + (v2.x + v3.x);
            ay += (v0.y + v1.y) + (v2.y + v3.y);
            az += (v0.z + v1.z) + (v2.z + v3.z);
            aw += (v0.w + v1.w) + (v2.w + v3.w);
        }
        for (; t < m; t += 4) {
            int e = t + r;
            int j = __shfl(idx, e & 63);
            if (e < m) {
                float4 v = in4[(size_t)j * 16 + q];
                ax += v.x; ay += v.y; az += v.z; aw += v.w;
            }
        }
    }

    // reduce across the 4 edge slots (lane bits 4,5); q preserved
    ax += __shfl_xor(ax, 16); ay += __shfl_xor(ay, 16);
    az += __shfl_xor(az, 16); aw += __shfl_xor(aw, 16);
    ax += __shfl_xor(ax, 32); ay += __shfl_xor(ay, 32);
    az += __shfl_xor(az, 32); aw += __shfl_xor(aw, 32);

    if (r == 0) {
        float tot[4] = {ax + self.x, ay + self.y, az + self.z, aw + self.w};
        float res[4];
        float dn = (float)(deg + 1);
#pragma unroll
        for (int jj = 0; jj < 4; ++jj) {
            int cc = q * 4 + jj;
            double mu  = st[cc] / (double)NND;
            double var = st[64 + cc] / (double)NND - mu * mu;
            if (var < 0.0) var = 0.0;
            double rs = 1.0 / sqrt(var + BN_EPS);
            double sc = (double)g[cc] * rs;
            float scf = (float)sc;
            float shf = (float)((double)b[cc] - mu * sc);
            res[jj] = scf * tot[jj] + dn * shf;
        }
        ((float4*)aggout)[(size_t)n * 16 + q] = make_float4(res[0], res[1], res[2], res[3]);
    }
}

// ---------------- MLP: h = relu(relu(agg @ W1) @ W2), in-place, + stats ----------------
__global__ __launch_bounds__(256) void k_mlp(float* __restrict__ h,
                                             double* __restrict__ statsout,
                                             const float* __restrict__ W1,
                                             const float* __restrict__ W2) {
    __shared__ float W1l[NH * NH];   // 16 KB
    __shared__ float W2l[NH * NH];   // 16 KB
    __shared__ float sT[64 * 68];    // 17 KB
    int tid = threadIdx.x;
    int base = blockIdx.x * 64;

    // issue all global loads first (weights + tile), then write
    float4 w1d[4], w2d[4], vd[4];
#pragma unroll
    for (int r = 0; r < 4; ++r) {
        int i4 = r * 256 + tid;
        w1d[r] = ((const float4*)W1)[i4];
        w2d[r] = ((const float4*)W2)[i4];
    }
#pragma unroll
    for (int s = 0; s < 4; ++s) {
        int i4 = s * 256 + tid;
        int n = i4 >> 4, q = i4 & 15;
        vd[s] = make_float4(0.f, 0.f, 0.f, 0.f);
        if (base + n < NND) vd[s] = ((const float4*)h)[(size_t)(base + n) * 16 + q];
    }
#pragma unroll
    for (int r = 0; r < 4; ++r) {
        int i4 = r * 256 + tid;
        ((float4*)W1l)[i4] = w1d[r];
        ((float4*)W2l)[i4] = w2d[r];
    }
#pragma unroll
    for (int s = 0; s < 4; ++s) {
        int i4 = s * 256 + tid;
        int n = i4 >> 4, q = i4 & 15;
        sT[(q * 4 + 0) * 68 + n] = vd[s].x;
        sT[(q * 4 + 1) * 68 + n] = vd[s].y;
        sT[(q * 4 + 2) * 68 + n] = vd[s].z;
        sT[(q * 4 + 3) * 68 + n] = vd[s].w;
    }
    __syncthreads();

    int tn = tid & 15, tc = tid >> 4;

    // GEMM1: t1 = relu(agg @ W1)
    float a1[4][4];
#pragma unroll
    for (int i = 0; i < 4; ++i)
#pragma unroll
        for (int j = 0; j < 4; ++j) a1[i][j] = 0.f;
#pragma unroll 8
    for (int k = 0; k < 64; ++k) {
        float4 a  = *(const float4*)&sT[k * 68 + tn * 4];
        float4 wv = *(const float4*)&W1l[k * NH + tc * 4];
        float av[4]  = {a.x, a.y, a.z, a.w};
        float wvv[4] = {wv.x, wv.y, wv.z, wv.w};
#pragma unroll
        for (int i = 0; i < 4; ++i)
#pragma unroll
            for (int j = 0; j < 4; ++j) a1[i][j] += av[i] * wvv[j];
    }
#pragma unroll
    for (int i = 0; i < 4; ++i)
#pragma unroll
        for (int j = 0; j < 4; ++j) a1[i][j] = fmaxf(a1[i][j], 0.f);

    __syncthreads();
#pragma unroll
    for (int j = 0; j < 4; ++j) {
        float4 t = {a1[0][j], a1[1][j], a1[2][j], a1[3][j]};
        *(float4*)&sT[(tc * 4 + j) * 68 + tn * 4] = t;
    }
    __syncthreads();

    // GEMM2: t2 = relu(t1 @ W2)
    float a2[4][4];
#pragma unroll
    for (int i = 0; i < 4; ++i)
#pragma unroll
        for (int j = 0; j < 4; ++j) a2[i][j] = 0.f;
#pragma unroll 8
    for (int k = 0; k < 64; ++k) {
        float4 a  = *(const float4*)&sT[k * 68 + tn * 4];
        float4 wv = *(const float4*)&W2l[k * NH + tc * 4];
        float av[4]  = {a.x, a.y, a.z, a.w};
        float wvv[4] = {wv.x, wv.y, wv.z, wv.w};
#pragma unroll
        for (int i = 0; i < 4; ++i)
#pragma unroll
            for (int j = 0; j < 4; ++j) a2[i][j] += av[i] * wvv[j];
    }

    double sum[4] = {0, 0, 0, 0}, ssq[4] = {0, 0, 0, 0};
#pragma unroll
    for (int i = 0; i < 4; ++i) {
        int n = base + tn * 4 + i;
        if (n < NND) {
            float o0 = fmaxf(a2[i][0], 0.f), o1 = fmaxf(a2[i][1], 0.f);
            float o2 = fmaxf(a2[i][2], 0.f), o3 = fmaxf(a2[i][3], 0.f);
            float4 o = {o0, o1, o2, o3};
            *(float4*)&h[(size_t)n * NH + tc * 4] = o;
            sum[0] += o0; ssq[0] += (double)o0 * o0;
            sum[1] += o1; ssq[1] += (double)o1 * o1;
            sum[2] += o2; ssq[2] += (double)o2 * o2;
            sum[3] += o3; ssq[3] += (double)o3 * o3;
        }
    }
#pragma unroll
    for (int m = 1; m < 16; m <<= 1) {
#pragma unroll
        for (int j = 0; j < 4; ++j) {
            sum[j] += __shfl_xor(sum[j], m);
            ssq[j] += __shfl_xor(ssq[j], m);
        }
    }
    if (tn == 0) {
#pragma unroll
        for (int j = 0; j < 4; ++j) {
            atomicAdd(&statsout[tc * 4 + j], sum[j]);
            atomicAdd(&statsout[64 + tc * 4 + j], ssq[j]);
        }
    }
}

// ---------------- final BN apply, in-place, finalize folded via LDS ----------------
__global__ void k_bnout(float* __restrict__ h, const double* __restrict__ st,
                        const float* __restrict__ g, const float* __restrict__ b) {
    __shared__ float sl[128];
    int tid = threadIdx.x;
    if (tid < 64) {
        double mu  = st[tid] / (double)NND;
        double var = st[64 + tid] / (double)NND - mu * mu;
        if (var < 0.0) var = 0.0;
        double rs = 1.0 / sqrt(var + BN_EPS);
        double sc = (double)g[tid] * rs;
        sl[tid]      = (float)sc;
        sl[64 + tid] = (float)((double)b[tid] - mu * sc);
    }
    __syncthreads();
    int i4 = blockIdx.x * 256 + tid;
    if (i4 < NND * NH / 4) {
        int cg = i4 & 15;
        float4 v   = ((float4*)h)[i4];
        float4 scv = *(float4*)&sl[cg * 4];
        float4 shv = *(float4*)&sl[64 + cg * 4];
        v.x = v.x * scv.x + shv.x;
        v.y = v.y * scv.y + shv.y;
        v.z = v.z * scv.z + shv.z;
        v.w = v.w * scv.w + shv.w;
        ((float4*)h)[i4] = v;
    }
}

extern "C" void kernel_launch(void* const* d_in, const int* in_sizes, int n_in,
                              void* d_out, int out_size, void* d_ws, size_t ws_size,
                              hipStream_t stream) {
    const float* x     = (const float*)d_in[0];
    const int*   ei    = (const int*)d_in[1];
    const float* Wt    = (const float*)d_in[2];
    const float* bt    = (const float*)d_in[3];
    const float* gt    = (const float*)d_in[4];
    const float* bbt   = (const float*)d_in[5];
    const float* W1    = (const float*)d_in[6];
    const float* W2    = (const float*)d_in[7];
    const float* gamma = (const float*)d_in[8];
    const float* beta  = (const float*)d_in[9];
    float* out = (float*)d_out;

    char* ws = (char*)d_ws;
    float*  hA    = (float*)(ws + WS_HA);
    double* stats = (double*)(ws + WS_STATS);
    int*    deg   = (int*)(ws + WS_DEG);
    int*    offs  = (int*)(ws + WS_OFFS);
    int*    cur   = (int*)(ws + WS_CUR);
    int*    esrc  = (int*)(ws + WS_ESRC);

    const int* srcv = ei;
    const int* dstv = ei + NED;

    hipMemsetAsync(stats, 0, 4 * 128 * 8, stream);
    hipMemsetAsync(deg, 0, NND * 4, stream);

    const int EB = (NED + 255) / 256;
    k_deg<<<EB, 256, 0, stream>>>(dstv, deg);
    k_scan<<<1, 1024, 0, stream>>>(deg, offs);
    hipMemcpyAsync(cur, offs, NND * 4, hipMemcpyDeviceToDevice, stream);
    k_fill<<<EB, 256, 0, stream>>>(srcv, dstv, cur, esrc);

    const int NT = (NND + 63) / 64;   // 782 tiles
    const int NB = NND / 4;           // 12500 agg blocks

    k_transform<<<NT, 256, 0, stream>>>(x, Wt, bt, hA, stats);

    // layer 0: hA --agg(BN0 folded)--> out --mlp--> out (+stats1)
    k_agg<<<NB, 256, 0, stream>>>(hA, out, stats, gt, bbt, offs, esrc);
    k_mlp<<<NT, 256, 0, stream>>>(out, stats + 128, W1, W2);

    // layer 1: out --agg(BN1 folded)--> hA --mlp--> hA (+stats2)
    k_agg<<<NB, 256, 0, stream>>>(out, hA, stats + 128, gamma, beta, offs, esrc);
    k_mlp<<<NT, 256, 0, stream>>>(hA, stats + 256, W1 + 4096, W2 + 4096);

    // layer 2: hA --agg(BN2 folded)--> out --mlp--> out (+stats3)
    k_agg<<<NB, 256, 0, stream>>>(hA, out, stats + 256, gamma + 64, beta + 64, offs, esrc);
    k_mlp<<<NT, 256, 0, stream>>>(out, stats + 384, W1 + 8192, W2 + 8192);

    // final BN apply (finalize folded)
    k_bnout<<<(NND * NH / 4 + 255) / 256, 256, 0, stream>>>(out, stats + 384, gamma + 128, beta + 128);
}

// Round 7
// 403.692 us; speedup vs baseline: 1.5693x; 1.5693x over previous
//
#include <hip/hip_runtime.h>

#define NND 50000
#define NED 800000
#define NF  128
#define NH  64
#define BN_EPS 1e-5
#define NCOPY 64   // stats slot-copies (contention 782/64 ~ 12 per address)

// ---- workspace byte offsets (16B aligned) ----
#define WS_HA     0                          // float[NND*64]          12,800,000 B
#define WS_STATS  12800000                   // double[NCOPY*128]      65,536 B (single stage, self-cleaned)
#define WS_SSF    (WS_STATS + NCOPY*128*8)   // float[128]             512 B (scale|shift)
#define WS_DEG    (WS_SSF + 512)             // int[NND]
#define WS_OFFS   (WS_DEG + NND*4)           // int[NND+4]
#define WS_CUR    (WS_OFFS + (NND+4)*4)      // int[NND]
#define WS_ESRC   (WS_CUR + NND*4)           // int[NED]

// ---------------- CSR build ----------------
__global__ void k_deg(const int* __restrict__ dst, int* __restrict__ deg) {
    int e = blockIdx.x * 256 + threadIdx.x;
    if (e < NED) atomicAdd(&deg[dst[e]], 1);
}

__global__ __launch_bounds__(1024) void k_scan(const int* __restrict__ deg,
                                               int* __restrict__ offs) {
    __shared__ int sd[1024];
    int t = threadIdx.x;
    const int C = (NND + 1023) / 1024;   // 49
    int s = t * C; if (s > NND) s = NND;
    int e = s + C; if (e > NND) e = NND;
    int loc = 0;
    for (int i = s; i < e; ++i) loc += deg[i];
    sd[t] = loc;
    __syncthreads();
    for (int off = 1; off < 1024; off <<= 1) {
        int v = (t >= off) ? sd[t - off] : 0;
        __syncthreads();
        sd[t] += v;
        __syncthreads();
    }
    int run = sd[t] - loc;
    for (int i = s; i < e; ++i) { offs[i] = run; run += deg[i]; }
    if (t == 1023) offs[NND] = sd[1023];
}

__global__ void k_fill(const int* __restrict__ src, const int* __restrict__ dst,
                       int* __restrict__ cur, int* __restrict__ esrc) {
    int e = blockIdx.x * 256 + threadIdx.x;
    if (e < NED) {
        int d = dst[e];
        int pos = atomicAdd(&cur[d], 1);
        esrc[pos] = src[e];
    }
}

// ---------------- BN finalize: reduce slot-copies -> float sc/sh; self-clean ----------------
__global__ void k_fin(double* __restrict__ st,
                      const float* __restrict__ g, const float* __restrict__ b,
                      float* __restrict__ ssout) {
    int c = threadIdx.x;   // 64 threads
    double sum = 0.0, ssq = 0.0;
    for (int cp = 0; cp < NCOPY; ++cp) {
        sum += st[cp * 128 + c];
        ssq += st[cp * 128 + 64 + c];
    }
    // self-clean for the next stage (and next graph replay)
    for (int cp = 0; cp < NCOPY; ++cp) {
        st[cp * 128 + c] = 0.0;
        st[cp * 128 + 64 + c] = 0.0;
    }
    double mu  = sum / (double)NND;
    double var = ssq / (double)NND - mu * mu;
    if (var < 0.0) var = 0.0;
    double rs = 1.0 / sqrt(var + BN_EPS);
    double sc = (double)g[c] * rs;
    ssout[c]      = (float)sc;
    ssout[64 + c] = (float)((double)b[c] - mu * sc);
}

// ---------------- input transform: wave-per-tile 8x8 GEMM, K=128 chunked ----------------
__global__ __launch_bounds__(128) void k_transform(const float* __restrict__ x,
                                                   const float* __restrict__ Wt,
                                                   const float* __restrict__ bt,
                                                   float* __restrict__ outraw,
                                                   double* __restrict__ stats) {
    __shared__ __align__(16) float Wl[NF * NH];        // 32 KB
    __shared__ __align__(16) float sTbuf[2 * 64 * 68]; // 2 x 17.4 KB
    int tid  = threadIdx.x;
    int wave = tid >> 6, lane = tid & 63;
    int ti = lane & 7, tj = lane >> 3;
    int tile = blockIdx.x * 2 + wave;                  // 0..781
    int base = tile * 64;
    float* sTw = &sTbuf[wave * 64 * 68];
    const float4* x4 = (const float4*)x;

    // stage Wt (2048 float4) cooperatively
#pragma unroll
    for (int r = 0; r < 16; ++r) {
        int i4 = r * 128 + tid;
        ((float4*)Wl)[i4] = ((const float4*)Wt)[i4];
    }

    float acc[8][8];
#pragma unroll
    for (int i = 0; i < 8; ++i)
#pragma unroll
        for (int j = 0; j < 8; ++j) acc[i][j] = 0.f;

    for (int ch = 0; ch < 2; ++ch) {
        __syncthreads();
        // stage x[:, ch*64 .. +63] transposed into sTw[k][node], stride 68
#pragma unroll
        for (int s = 0; s < 16; ++s) {
            int flat = s * 64 + lane;
            int nl = flat >> 4, q = flat & 15;
            float4 v = {0.f, 0.f, 0.f, 0.f};
            if (base + nl < NND) v = x4[(size_t)(base + nl) * 32 + ch * 16 + q];
            sTw[(q * 4 + 0) * 68 + nl] = v.x;
            sTw[(q * 4 + 1) * 68 + nl] = v.y;
            sTw[(q * 4 + 2) * 68 + nl] = v.z;
            sTw[(q * 4 + 3) * 68 + nl] = v.w;
        }
        __syncthreads();
#pragma unroll 2
        for (int k = 0; k < 64; ++k) {
            const float* ap = &sTw[k * 68 + ti * 8];
            float4 alo = *(const float4*)ap;
            float4 ahi = *(const float4*)(ap + 4);
            const float* wp = &Wl[(ch * 64 + k) * NH + tj * 8];
            float4 wlo = *(const float4*)wp;
            float4 whi = *(const float4*)(wp + 4);
            float a8[8] = {alo.x, alo.y, alo.z, alo.w, ahi.x, ahi.y, ahi.z, ahi.w};
            float w8[8] = {wlo.x, wlo.y, wlo.z, wlo.w, whi.x, whi.y, whi.z, whi.w};
#pragma unroll
            for (int i = 0; i < 8; ++i)
#pragma unroll
                for (int j = 0; j < 8; ++j) acc[i][j] += a8[i] * w8[j];
        }
    }

    float b8[8];
    *(float4*)&b8[0] = ((const float4*)bt)[tj * 2];
    *(float4*)&b8[4] = ((const float4*)bt)[tj * 2 + 1];

    float s8[8], q8[8];
#pragma unroll
    for (int j = 0; j < 8; ++j) { s8[j] = 0.f; q8[j] = 0.f; }
#pragma unroll
    for (int i = 0; i < 8; ++i) {
        int n = base + ti * 8 + i;
        if (n < NND) {
            float o[8];
#pragma unroll
            for (int j = 0; j < 8; ++j) {
                o[j] = acc[i][j] + b8[j];
                s8[j] += o[j];
                q8[j] += o[j] * o[j];
            }
            *(float4*)&outraw[(size_t)n * NH + tj * 8]     = *(float4*)&o[0];
            *(float4*)&outraw[(size_t)n * NH + tj * 8 + 4] = *(float4*)&o[4];
        }
    }
#pragma unroll
    for (int m = 1; m < 8; m <<= 1) {
#pragma unroll
        for (int j = 0; j < 8; ++j) {
            s8[j] += __shfl_xor(s8[j], m);
            q8[j] += __shfl_xor(q8[j], m);
        }
    }
    if (ti == 0) {
        int slot = (tile & (NCOPY - 1)) * 128 + tj * 8;
#pragma unroll
        for (int j = 0; j < 8; ++j) {
            atomicAdd(&stats[slot + j], (double)s8[j]);
            atomicAdd(&stats[slot + 64 + j], (double)q8[j]);
        }
    }
}

// ---------------- aggregation: wave-per-node, float4 gather, BN via precomputed sc/sh ----------------
__global__ __launch_bounds__(256) void k_agg(const float* __restrict__ inraw,
                                             float* __restrict__ aggout,
                                             const float* __restrict__ ss,
                                             const int* __restrict__ offs,
                                             const int* __restrict__ esrc) {
    int tid  = threadIdx.x;
    int lane = tid & 63;
    int wv   = tid >> 6;
    int n = blockIdx.x * 4 + wv;
    int q = lane & 15;
    int r = lane >> 4;
    const float4* in4 = (const float4*)inraw;

    int e0 = offs[n], e1 = offs[n + 1];
    int deg = e1 - e0;

    float4 self = make_float4(0.f, 0.f, 0.f, 0.f);
    if (r == 0) self = in4[(size_t)n * 16 + q];

    float ax = 0.f, ay = 0.f, az = 0.f, aw = 0.f;
    for (int bb = e0; bb < e1; bb += 64) {
        int m = e1 - bb; if (m > 64) m = 64;
        int idx = (lane < m) ? esrc[bb + lane] : 0;
        int t = 0;
        for (; t + 16 <= m; t += 16) {
            int j0 = __shfl(idx, t + r);
            int j1 = __shfl(idx, t + 4 + r);
            int j2 = __shfl(idx, t + 8 + r);
            int j3 = __shfl(idx, t + 12 + r);
            float4 v0 = in4[(size_t)j0 * 16 + q];
            float4 v1 = in4[(size_t)j1 * 16 + q];
            float4 v2 = in4[(size_t)j2 * 16 + q];
            float4 v3 = in4[(size_t)j3 * 16 + q];
            ax += (v0.x + v1.x) + (v2.x + v3.x);
            ay += (v0.y + v1.y) + (v2.y + v3.y);
            az += (v0.z + v1.z) + (v2.z + v3.z);
            aw += (v0.w + v1.w) + (v2.w + v3.w);
        }
        for (; t < m; t += 4) {
            int e = t + r;
            int j = __shfl(idx, e & 63);
            if (e < m) {
                float4 v = in4[(size_t)j * 16 + q];
                ax += v.x; ay += v.y; az += v.z; aw += v.w;
            }
        }
    }

    ax += __shfl_xor(ax, 16); ay += __shfl_xor(ay, 16);
    az += __shfl_xor(az, 16); aw += __shfl_xor(aw, 16);
    ax += __shfl_xor(ax, 32); ay += __shfl_xor(ay, 32);
    az += __shfl_xor(az, 32); aw += __shfl_xor(aw, 32);

    if (r == 0) {
        float4 sc4 = ((const float4*)ss)[q];
        float4 sh4 = ((const float4*)(ss + 64))[q];
        float dn = (float)(deg + 1);
        float4 res;
        res.x = sc4.x * (ax + self.x) + dn * sh4.x;
        res.y = sc4.y * (ay + self.y) + dn * sh4.y;
        res.z = sc4.z * (az + self.z) + dn * sh4.z;
        res.w = sc4.w * (aw + self.w) + dn * sh4.w;
        ((float4*)aggout)[(size_t)n * 16 + q] = res;
    }
}

// ---------------- MLP: wave-per-tile 8x8 GEMM x2, relu, in-place, + stats partials ----------------
__global__ __launch_bounds__(128) void k_mlp(float* __restrict__ h,
                                             double* __restrict__ statsout,
                                             const float* __restrict__ W1,
                                             const float* __restrict__ W2) {
    __shared__ __align__(16) float W1l[NH * NH];       // 16 KB
    __shared__ __align__(16) float W2l[NH * NH];       // 16 KB
    __shared__ __align__(16) float sTbuf[2 * 64 * 68]; // 2 x 17.4 KB
    int tid  = threadIdx.x;
    int wave = tid >> 6, lane = tid & 63;
    int ti = lane & 7, tj = lane >> 3;
    int tile = blockIdx.x * 2 + wave;
    int base = tile * 64;
    float* sTw = &sTbuf[wave * 64 * 68];
    const float4* h4 = (const float4*)h;

    // stage weights (1024 float4 each)
#pragma unroll
    for (int r = 0; r < 8; ++r) {
        int i4 = r * 128 + tid;
        ((float4*)W1l)[i4] = ((const float4*)W1)[i4];
        ((float4*)W2l)[i4] = ((const float4*)W2)[i4];
    }
    // stage own tile transposed into sTw[k][node]
#pragma unroll
    for (int s = 0; s < 16; ++s) {
        int flat = s * 64 + lane;
        int nl = flat >> 4, q = flat & 15;
        float4 v = {0.f, 0.f, 0.f, 0.f};
        if (base + nl < NND) v = h4[(size_t)(base + nl) * 16 + q];
        sTw[(q * 4 + 0) * 68 + nl] = v.x;
        sTw[(q * 4 + 1) * 68 + nl] = v.y;
        sTw[(q * 4 + 2) * 68 + nl] = v.z;
        sTw[(q * 4 + 3) * 68 + nl] = v.w;
    }
    __syncthreads();

    // GEMM1: t1 = relu(agg @ W1)
    float acc[8][8];
#pragma unroll
    for (int i = 0; i < 8; ++i)
#pragma unroll
        for (int j = 0; j < 8; ++j) acc[i][j] = 0.f;
#pragma unroll 2
    for (int k = 0; k < 64; ++k) {
        const float* ap = &sTw[k * 68 + ti * 8];
        float4 alo = *(const float4*)ap;
        float4 ahi = *(const float4*)(ap + 4);
        const float* wp = &W1l[k * NH + tj * 8];
        float4 wlo = *(const float4*)wp;
        float4 whi = *(const float4*)(wp + 4);
        float a8[8] = {alo.x, alo.y, alo.z, alo.w, ahi.x, ahi.y, ahi.z, ahi.w};
        float w8[8] = {wlo.x, wlo.y, wlo.z, wlo.w, whi.x, whi.y, whi.z, whi.w};
#pragma unroll
        for (int i = 0; i < 8; ++i)
#pragma unroll
            for (int j = 0; j < 8; ++j) acc[i][j] += a8[i] * w8[j];
    }
#pragma unroll
    for (int i = 0; i < 8; ++i)
#pragma unroll
        for (int j = 0; j < 8; ++j) acc[i][j] = fmaxf(acc[i][j], 0.f);

    __syncthreads();
    // transpose-write t1 into sTw[col][node]
#pragma unroll
    for (int j = 0; j < 8; ++j) {
        float* p = &sTw[(tj * 8 + j) * 68 + ti * 8];
        float4 lo = {acc[0][j], acc[1][j], acc[2][j], acc[3][j]};
        float4 hi = {acc[4][j], acc[5][j], acc[6][j], acc[7][j]};
        *(float4*)p = lo;
        *(float4*)(p + 4) = hi;
    }
    __syncthreads();

    // GEMM2: out = relu(t1 @ W2)
    float a2[8][8];
#pragma unroll
    for (int i = 0; i < 8; ++i)
#pragma unroll
        for (int j = 0; j < 8; ++j) a2[i][j] = 0.f;
#pragma unroll 2
    for (int k = 0; k < 64; ++k) {
        const float* ap = &sTw[k * 68 + ti * 8];
        float4 alo = *(const float4*)ap;
        float4 ahi = *(const float4*)(ap + 4);
        const float* wp = &W2l[k * NH + tj * 8];
        float4 wlo = *(const float4*)wp;
        float4 whi = *(const float4*)(wp + 4);
        float a8[8] = {alo.x, alo.y, alo.z, alo.w, ahi.x, ahi.y, ahi.z, ahi.w};
        float w8[8] = {wlo.x, wlo.y, wlo.z, wlo.w, whi.x, whi.y, whi.z, whi.w};
#pragma unroll
        for (int i = 0; i < 8; ++i)
#pragma unroll
            for (int j = 0; j < 8; ++j) a2[i][j] += a8[i] * w8[j];
    }

    float s8[8], q8[8];
#pragma unroll
    for (int j = 0; j < 8; ++j) { s8[j] = 0.f; q8[j] = 0.f; }
#pragma unroll
    for (int i = 0; i < 8; ++i) {
        int n = base + ti * 8 + i;
        if (n < NND) {
            float o[8];
#pragma unroll
            for (int j = 0; j < 8; ++j) {
                o[j] = fmaxf(a2[i][j], 0.f);
                s8[j] += o[j];
                q8[j] += o[j] * o[j];
            }
            *(float4*)&h[(size_t)n * NH + tj * 8]     = *(float4*)&o[0];
            *(float4*)&h[(size_t)n * NH + tj * 8 + 4] = *(float4*)&o[4];
        }
    }
#pragma unroll
    for (int m = 1; m < 8; m <<= 1) {
#pragma unroll
        for (int j = 0; j < 8; ++j) {
            s8[j] += __shfl_xor(s8[j], m);
            q8[j] += __shfl_xor(q8[j], m);
        }
    }
    if (ti == 0) {
        int slot = (tile & (NCOPY - 1)) * 128 + tj * 8;
#pragma unroll
        for (int j = 0; j < 8; ++j) {
            atomicAdd(&statsout[slot + j], (double)s8[j]);
            atomicAdd(&statsout[slot + 64 + j], (double)q8[j]);
        }
    }
}

// ---------------- final BN apply, in-place, sc/sh precomputed ----------------
__global__ void k_bnout(float* __restrict__ h, const float* __restrict__ ss) {
    int i4 = blockIdx.x * 256 + threadIdx.x;
    if (i4 < NND * NH / 4) {
        int cg = i4 & 15;
        float4 v   = ((float4*)h)[i4];
        float4 scv = ((const float4*)ss)[cg];
        float4 shv = ((const float4*)(ss + 64))[cg];
        v.x = v.x * scv.x + shv.x;
        v.y = v.y * scv.y + shv.y;
        v.z = v.z * scv.z + shv.z;
        v.w = v.w * scv.w + shv.w;
        ((float4*)h)[i4] = v;
    }
}

extern "C" void kernel_launch(void* const* d_in, const int* in_sizes, int n_in,
                              void* d_out, int out_size, void* d_ws, size_t ws_size,
                              hipStream_t stream) {
    const float* x     = (const float*)d_in[0];
    const int*   ei    = (const int*)d_in[1];
    const float* Wt    = (const float*)d_in[2];
    const float* bt    = (const float*)d_in[3];
    const float* gt    = (const float*)d_in[4];
    const float* bbt   = (const float*)d_in[5];
    const float* W1    = (const float*)d_in[6];
    const float* W2    = (const float*)d_in[7];
    const float* gamma = (const float*)d_in[8];
    const float* beta  = (const float*)d_in[9];
    float* out = (float*)d_out;

    char* ws = (char*)d_ws;
    float*  hA    = (float*)(ws + WS_HA);
    double* stats = (double*)(ws + WS_STATS);
    float*  ssf   = (float*)(ws + WS_SSF);
    int*    deg   = (int*)(ws + WS_DEG);
    int*    offs  = (int*)(ws + WS_OFFS);
    int*    cur   = (int*)(ws + WS_CUR);
    int*    esrc  = (int*)(ws + WS_ESRC);

    const int* srcv = ei;
    const int* dstv = ei + NED;

    // one memset covers stats + ssf + deg (contiguous)
    hipMemsetAsync(stats, 0, NCOPY * 128 * 8 + 512 + NND * 4, stream);

    const int EB = (NED + 255) / 256;
    k_deg<<<EB, 256, 0, stream>>>(dstv, deg);
    k_scan<<<1, 1024, 0, stream>>>(deg, offs);
    hipMemcpyAsync(cur, offs, NND * 4, hipMemcpyDeviceToDevice, stream);
    k_fill<<<EB, 256, 0, stream>>>(srcv, dstv, cur, esrc);

    const int NT2 = 391;            // 782 tiles / 2 waves per block
    const int NB  = NND / 4;        // 12500 agg blocks

    k_transform<<<NT2, 128, 0, stream>>>(x, Wt, bt, hA, stats);
    k_fin<<<1, 64, 0, stream>>>(stats, gt, bbt, ssf);

    // layer 0: hA --agg--> out --mlp(in-place)--> out
    k_agg<<<NB, 256, 0, stream>>>(hA, out, ssf, offs, esrc);
    k_mlp<<<NT2, 128, 0, stream>>>(out, stats, W1, W2);
    k_fin<<<1, 64, 0, stream>>>(stats, gamma, beta, ssf);

    // layer 1: out --agg--> hA --mlp--> hA
    k_agg<<<NB, 256, 0, stream>>>(out, hA, ssf, offs, esrc);
    k_mlp<<<NT2, 128, 0, stream>>>(hA, stats, W1 + 4096, W2 + 4096);
    k_fin<<<1, 64, 0, stream>>>(stats, gamma + 64, beta + 64, ssf);

    // layer 2: hA --agg--> out --mlp--> out
    k_agg<<<NB, 256, 0, stream>>>(hA, out, ssf, offs, esrc);
    k_mlp<<<NT2, 128, 0, stream>>>(out, stats, W1 + 8192, W2 + 8192);
    k_fin<<<1, 64, 0, stream>>>(stats, gamma + 128, beta + 128, ssf);

    k_bnout<<<(NND * NH / 4 + 255) / 256, 256, 0, stream>>>(out, ssf);
}

// Round 8
// 330.320 us; speedup vs baseline: 1.9178x; 1.2221x over previous
//
#include <hip/hip_runtime.h>

#define NND 50000
#define NED 800000
#define NF  128
#define NH  64
#define BN_EPS 1e-5
#define NCOPY 64   // stats slot-copies (contention 782/64 ~ 12 per address)
#define SCB  256   // scan chunk
#define NSB  ((NND + SCB - 1) / SCB)   // 196 scan blocks

// ---- workspace byte offsets (16B aligned) ----
#define WS_HA     0                          // float[NND*64]          12,800,000 B
#define WS_STATS  12800000                   // double[NCOPY*128]      65,536 B (self-cleaned by k_fin)
#define WS_SSF    (WS_STATS + NCOPY*128*8)   // float[128]             512 B (scale|shift)
#define WS_DEG    (WS_SSF + 512)             // int[NND]   (memset'd with stats+ssf each call)
#define WS_OFFS   (WS_DEG + NND*4)           // int[NND+4]
#define WS_CUR    (WS_OFFS + (NND+4)*4)      // int[NND]
#define WS_PARTS  (WS_CUR + NND*4)           // int[256]
#define WS_ESRC   (WS_PARTS + 256*4)         // int[NED]

// ---------------- CSR build ----------------
__global__ void k_deg(const int* __restrict__ dst, int* __restrict__ deg) {
    int e4 = blockIdx.x * 256 + threadIdx.x;          // 4 edges per thread
    if (e4 * 4 < NED) {
        int4 d = ((const int4*)dst)[e4];
        atomicAdd(&deg[d.x], 1);
        atomicAdd(&deg[d.y], 1);
        atomicAdd(&deg[d.z], 1);
        atomicAdd(&deg[d.w], 1);
    }
}

// pass 1: per-256-chunk exclusive scan into offs, chunk totals into parts
__global__ __launch_bounds__(SCB) void k_part(const int* __restrict__ deg,
                                              int* __restrict__ offs,
                                              int* __restrict__ parts) {
    __shared__ int sd[SCB];
    int t = threadIdx.x;
    int i = blockIdx.x * SCB + t;
    int v = (i < NND) ? deg[i] : 0;
    sd[t] = v;
    __syncthreads();
#pragma unroll
    for (int off = 1; off < SCB; off <<= 1) {
        int u = (t >= off) ? sd[t - off] : 0;
        __syncthreads();
        sd[t] += u;
        __syncthreads();
    }
    if (i < NND) offs[i] = sd[t] - v;                 // block-local exclusive
    if (t == SCB - 1) parts[blockIdx.x] = sd[t];
}

// pass 2: exclusive scan of the 196 partials (single tiny block)
__global__ __launch_bounds__(256) void k_scan2(int* __restrict__ parts) {
    __shared__ int sd[256];
    int t = threadIdx.x;
    int v = (t < NSB) ? parts[t] : 0;
    sd[t] = v;
    __syncthreads();
#pragma unroll
    for (int off = 1; off < 256; off <<= 1) {
        int u = (t >= off) ? sd[t - off] : 0;
        __syncthreads();
        sd[t] += u;
        __syncthreads();
    }
    if (t < NSB) parts[t] = sd[t] - v;                // exclusive
}

// pass 3: add block offsets; write cur=offs; offs[NND]=NED (constant)
__global__ __launch_bounds__(256) void k_apply(int* __restrict__ offs,
                                               const int* __restrict__ parts,
                                               int* __restrict__ cur) {
    int i = blockIdx.x * 256 + threadIdx.x;
    if (i < NND) {
        int o = offs[i] + parts[i >> 8];
        offs[i] = o;
        cur[i] = o;
    }
    if (i == NND) offs[NND] = NED;
}

__global__ void k_fill(const int* __restrict__ src, const int* __restrict__ dst,
                       int* __restrict__ cur, int* __restrict__ esrc) {
    int e4 = blockIdx.x * 256 + threadIdx.x;          // 4 edges per thread
    if (e4 * 4 < NED) {
        int4 d = ((const int4*)dst)[e4];
        int4 s = ((const int4*)src)[e4];
        esrc[atomicAdd(&cur[d.x], 1)] = s.x;
        esrc[atomicAdd(&cur[d.y], 1)] = s.y;
        esrc[atomicAdd(&cur[d.z], 1)] = s.z;
        esrc[atomicAdd(&cur[d.w], 1)] = s.w;
    }
}

// ---------------- BN finalize: reduce slot-copies -> float sc/sh; self-clean ----------------
__global__ void k_fin(double* __restrict__ st,
                      const float* __restrict__ g, const float* __restrict__ b,
                      float* __restrict__ ssout) {
    int c = threadIdx.x;   // 64 threads
    double sum = 0.0, ssq = 0.0;
    for (int cp = 0; cp < NCOPY; ++cp) {
        sum += st[cp * 128 + c];
        ssq += st[cp * 128 + 64 + c];
    }
    for (int cp = 0; cp < NCOPY; ++cp) {
        st[cp * 128 + c] = 0.0;
        st[cp * 128 + 64 + c] = 0.0;
    }
    double mu  = sum / (double)NND;
    double var = ssq / (double)NND - mu * mu;
    if (var < 0.0) var = 0.0;
    double rs = 1.0 / sqrt(var + BN_EPS);
    double sc = (double)g[c] * rs;
    ssout[c]      = (float)sc;
    ssout[64 + c] = (float)((double)b[c] - mu * sc);
}

// ---------------- input transform: wave-per-tile 8x8 GEMM, K=128 chunked ----------------
__global__ __launch_bounds__(128) void k_transform(const float* __restrict__ x,
                                                   const float* __restrict__ Wt,
                                                   const float* __restrict__ bt,
                                                   float* __restrict__ outraw,
                                                   double* __restrict__ stats) {
    __shared__ __align__(16) float Wl[NF * NH];        // 32 KB
    __shared__ __align__(16) float sTbuf[2 * 64 * 68]; // 2 x 17.4 KB
    int tid  = threadIdx.x;
    int wave = tid >> 6, lane = tid & 63;
    int ti = lane & 7, tj = lane >> 3;
    int tile = blockIdx.x * 2 + wave;                  // 0..781
    int base = tile * 64;
    float* sTw = &sTbuf[wave * 64 * 68];
    const float4* x4 = (const float4*)x;

#pragma unroll
    for (int r = 0; r < 16; ++r) {
        int i4 = r * 128 + tid;
        ((float4*)Wl)[i4] = ((const float4*)Wt)[i4];
    }

    float acc[8][8];
#pragma unroll
    for (int i = 0; i < 8; ++i)
#pragma unroll
        for (int j = 0; j < 8; ++j) acc[i][j] = 0.f;

    for (int ch = 0; ch < 2; ++ch) {
        __syncthreads();
#pragma unroll
        for (int s = 0; s < 16; ++s) {
            int flat = s * 64 + lane;
            int nl = flat >> 4, q = flat & 15;
            float4 v = {0.f, 0.f, 0.f, 0.f};
            if (base + nl < NND) v = x4[(size_t)(base + nl) * 32 + ch * 16 + q];
            sTw[(q * 4 + 0) * 68 + nl] = v.x;
            sTw[(q * 4 + 1) * 68 + nl] = v.y;
            sTw[(q * 4 + 2) * 68 + nl] = v.z;
            sTw[(q * 4 + 3) * 68 + nl] = v.w;
        }
        __syncthreads();
#pragma unroll 2
        for (int k = 0; k < 64; ++k) {
            const float* ap = &sTw[k * 68 + ti * 8];
            float4 alo = *(const float4*)ap;
            float4 ahi = *(const float4*)(ap + 4);
            const float* wp = &Wl[(ch * 64 + k) * NH + tj * 8];
            float4 wlo = *(const float4*)wp;
            float4 whi = *(const float4*)(wp + 4);
            float a8[8] = {alo.x, alo.y, alo.z, alo.w, ahi.x, ahi.y, ahi.z, ahi.w};
            float w8[8] = {wlo.x, wlo.y, wlo.z, wlo.w, whi.x, whi.y, whi.z, whi.w};
#pragma unroll
            for (int i = 0; i < 8; ++i)
#pragma unroll
                for (int j = 0; j < 8; ++j) acc[i][j] += a8[i] * w8[j];
        }
    }

    float b8[8];
    *(float4*)&b8[0] = ((const float4*)bt)[tj * 2];
    *(float4*)&b8[4] = ((const float4*)bt)[tj * 2 + 1];

    float s8[8], q8[8];
#pragma unroll
    for (int j = 0; j < 8; ++j) { s8[j] = 0.f; q8[j] = 0.f; }
#pragma unroll
    for (int i = 0; i < 8; ++i) {
        int n = base + ti * 8 + i;
        if (n < NND) {
            float o[8];
#pragma unroll
            for (int j = 0; j < 8; ++j) {
                o[j] = acc[i][j] + b8[j];
                s8[j] += o[j];
                q8[j] += o[j] * o[j];
            }
            *(float4*)&outraw[(size_t)n * NH + tj * 8]     = *(float4*)&o[0];
            *(float4*)&outraw[(size_t)n * NH + tj * 8 + 4] = *(float4*)&o[4];
        }
    }
#pragma unroll
    for (int m = 1; m < 8; m <<= 1) {
#pragma unroll
        for (int j = 0; j < 8; ++j) {
            s8[j] += __shfl_xor(s8[j], m);
            q8[j] += __shfl_xor(q8[j], m);
        }
    }
    if (ti == 0) {
        int slot = (tile & (NCOPY - 1)) * 128 + tj * 8;
#pragma unroll
        for (int j = 0; j < 8; ++j) {
            atomicAdd(&stats[slot + j], (double)s8[j]);
            atomicAdd(&stats[slot + 64 + j], (double)q8[j]);
        }
    }
}

// ---------------- aggregation: wave-per-node, float4 gather, BN via precomputed sc/sh ----------------
__global__ __launch_bounds__(256) void k_agg(const float* __restrict__ inraw,
                                             float* __restrict__ aggout,
                                             const float* __restrict__ ss,
                                             const int* __restrict__ offs,
                                             const int* __restrict__ esrc) {
    int tid  = threadIdx.x;
    int lane = tid & 63;
    int wv   = tid >> 6;
    int n = blockIdx.x * 4 + wv;
    int q = lane & 15;
    int r = lane >> 4;
    const float4* in4 = (const float4*)inraw;

    int e0 = offs[n], e1 = offs[n + 1];
    int deg = e1 - e0;

    float4 self = make_float4(0.f, 0.f, 0.f, 0.f);
    if (r == 0) self = in4[(size_t)n * 16 + q];

    float ax = 0.f, ay = 0.f, az = 0.f, aw = 0.f;
    for (int bb = e0; bb < e1; bb += 64) {
        int m = e1 - bb; if (m > 64) m = 64;
        int idx = (lane < m) ? esrc[bb + lane] : 0;
        int t = 0;
        for (; t + 16 <= m; t += 16) {
            int j0 = __shfl(idx, t + r);
            int j1 = __shfl(idx, t + 4 + r);
            int j2 = __shfl(idx, t + 8 + r);
            int j3 = __shfl(idx, t + 12 + r);
            float4 v0 = in4[(size_t)j0 * 16 + q];
            float4 v1 = in4[(size_t)j1 * 16 + q];
            float4 v2 = in4[(size_t)j2 * 16 + q];
            float4 v3 = in4[(size_t)j3 * 16 + q];
            ax += (v0.x + v1.x) + (v2.x + v3.x);
            ay += (v0.y + v1.y) + (v2.y + v3.y);
            az += (v0.z + v1.z) + (v2.z + v3.z);
            aw += (v0.w + v1.w) + (v2.w + v3.w);
        }
        for (; t < m; t += 4) {
            int e = t + r;
            int j = __shfl(idx, e & 63);
            if (e < m) {
                float4 v = in4[(size_t)j * 16 + q];
                ax += v.x; ay += v.y; az += v.z; aw += v.w;
            }
        }
    }

    ax += __shfl_xor(ax, 16); ay += __shfl_xor(ay, 16);
    az += __shfl_xor(az, 16); aw += __shfl_xor(aw, 16);
    ax += __shfl_xor(ax, 32); ay += __shfl_xor(ay, 32);
    az += __shfl_xor(az, 32); aw += __shfl_xor(aw, 32);

    if (r == 0) {
        float4 sc4 = ((const float4*)ss)[q];
        float4 sh4 = ((const float4*)(ss + 64))[q];
        float dn = (float)(deg + 1);
        float4 res;
        res.x = sc4.x * (ax + self.x) + dn * sh4.x;
        res.y = sc4.y * (ay + self.y) + dn * sh4.y;
        res.z = sc4.z * (az + self.z) + dn * sh4.z;
        res.w = sc4.w * (aw + self.w) + dn * sh4.w;
        ((float4*)aggout)[(size_t)n * 16 + q] = res;
    }
}

// ---------------- MLP: wave-per-tile 8x8 GEMM x2, relu, in-place, + stats partials ----------------
__global__ __launch_bounds__(128) void k_mlp(float* __restrict__ h,
                                             double* __restrict__ statsout,
                                             const float* __restrict__ W1,
                                             const float* __restrict__ W2) {
    __shared__ __align__(16) float W1l[NH * NH];       // 16 KB
    __shared__ __align__(16) float W2l[NH * NH];       // 16 KB
    __shared__ __align__(16) float sTbuf[2 * 64 * 68]; // 2 x 17.4 KB
    int tid  = threadIdx.x;
    int wave = tid >> 6, lane = tid & 63;
    int ti = lane & 7, tj = lane >> 3;
    int tile = blockIdx.x * 2 + wave;
    int base = tile * 64;
    float* sTw = &sTbuf[wave * 64 * 68];
    const float4* h4 = (const float4*)h;

#pragma unroll
    for (int r = 0; r < 8; ++r) {
        int i4 = r * 128 + tid;
        ((float4*)W1l)[i4] = ((const float4*)W1)[i4];
        ((float4*)W2l)[i4] = ((const float4*)W2)[i4];
    }
#pragma unroll
    for (int s = 0; s < 16; ++s) {
        int flat = s * 64 + lane;
        int nl = flat >> 4, q = flat & 15;
        float4 v = {0.f, 0.f, 0.f, 0.f};
        if (base + nl < NND) v = h4[(size_t)(base + nl) * 16 + q];
        sTw[(q * 4 + 0) * 68 + nl] = v.x;
        sTw[(q * 4 + 1) * 68 + nl] = v.y;
        sTw[(q * 4 + 2) * 68 + nl] = v.z;
        sTw[(q * 4 + 3) * 68 + nl] = v.w;
    }
    __syncthreads();

    float acc[8][8];
#pragma unroll
    for (int i = 0; i < 8; ++i)
#pragma unroll
        for (int j = 0; j < 8; ++j) acc[i][j] = 0.f;
#pragma unroll 2
    for (int k = 0; k < 64; ++k) {
        const float* ap = &sTw[k * 68 + ti * 8];
        float4 alo = *(const float4*)ap;
        float4 ahi = *(const float4*)(ap + 4);
        const float* wp = &W1l[k * NH + tj * 8];
        float4 wlo = *(const float4*)wp;
        float4 whi = *(const float4*)(wp + 4);
        float a8[8] = {alo.x, alo.y, alo.z, alo.w, ahi.x, ahi.y, ahi.z, ahi.w};
        float w8[8] = {wlo.x, wlo.y, wlo.z, wlo.w, whi.x, whi.y, whi.z, whi.w};
#pragma unroll
        for (int i = 0; i < 8; ++i)
#pragma unroll
            for (int j = 0; j < 8; ++j) acc[i][j] += a8[i] * w8[j];
    }
#pragma unroll
    for (int i = 0; i < 8; ++i)
#pragma unroll
        for (int j = 0; j < 8; ++j) acc[i][j] = fmaxf(acc[i][j], 0.f);

    __syncthreads();
#pragma unroll
    for (int j = 0; j < 8; ++j) {
        float* p = &sTw[(tj * 8 + j) * 68 + ti * 8];
        float4 lo = {acc[0][j], acc[1][j], acc[2][j], acc[3][j]};
        float4 hi = {acc[4][j], acc[5][j], acc[6][j], acc[7][j]};
        *(float4*)p = lo;
        *(float4*)(p + 4) = hi;
    }
    __syncthreads();

    float a2[8][8];
#pragma unroll
    for (int i = 0; i < 8; ++i)
#pragma unroll
        for (int j = 0; j < 8; ++j) a2[i][j] = 0.f;
#pragma unroll 2
    for (int k = 0; k < 64; ++k) {
        const float* ap = &sTw[k * 68 + ti * 8];
        float4 alo = *(const float4*)ap;
        float4 ahi = *(const float4*)(ap + 4);
        const float* wp = &W2l[k * NH + tj * 8];
        float4 wlo = *(const float4*)wp;
        float4 whi = *(const float4*)(wp + 4);
        float a8[8] = {alo.x, alo.y, alo.z, alo.w, ahi.x, ahi.y, ahi.z, ahi.w};
        float w8[8] = {wlo.x, wlo.y, wlo.z, wlo.w, whi.x, whi.y, whi.z, whi.w};
#pragma unroll
        for (int i = 0; i < 8; ++i)
#pragma unroll
            for (int j = 0; j < 8; ++j) a2[i][j] += a8[i] * w8[j];
    }

    float s8[8], q8[8];
#pragma unroll
    for (int j = 0; j < 8; ++j) { s8[j] = 0.f; q8[j] = 0.f; }
#pragma unroll
    for (int i = 0; i < 8; ++i) {
        int n = base + ti * 8 + i;
        if (n < NND) {
            float o[8];
#pragma unroll
            for (int j = 0; j < 8; ++j) {
                o[j] = fmaxf(a2[i][j], 0.f);
                s8[j] += o[j];
                q8[j] += o[j] * o[j];
            }
            *(float4*)&h[(size_t)n * NH + tj * 8]     = *(float4*)&o[0];
            *(float4*)&h[(size_t)n * NH + tj * 8 + 4] = *(float4*)&o[4];
        }
    }
#pragma unroll
    for (int m = 1; m < 8; m <<= 1) {
#pragma unroll
        for (int j = 0; j < 8; ++j) {
            s8[j] += __shfl_xor(s8[j], m);
            q8[j] += __shfl_xor(q8[j], m);
        }
    }
    if (ti == 0) {
        int slot = (tile & (NCOPY - 1)) * 128 + tj * 8;
#pragma unroll
        for (int j = 0; j < 8; ++j) {
            atomicAdd(&statsout[slot + j], (double)s8[j]);
            atomicAdd(&statsout[slot + 64 + j], (double)q8[j]);
        }
    }
}

// ---------------- final BN apply, in-place, sc/sh precomputed ----------------
__global__ void k_bnout(float* __restrict__ h, const float* __restrict__ ss) {
    int i4 = blockIdx.x * 256 + threadIdx.x;
    if (i4 < NND * NH / 4) {
        int cg = i4 & 15;
        float4 v   = ((float4*)h)[i4];
        float4 scv = ((const float4*)ss)[cg];
        float4 shv = ((const float4*)(ss + 64))[cg];
        v.x = v.x * scv.x + shv.x;
        v.y = v.y * scv.y + shv.y;
        v.z = v.z * scv.z + shv.z;
        v.w = v.w * scv.w + shv.w;
        ((float4*)h)[i4] = v;
    }
}

extern "C" void kernel_launch(void* const* d_in, const int* in_sizes, int n_in,
                              void* d_out, int out_size, void* d_ws, size_t ws_size,
                              hipStream_t stream) {
    const float* x     = (const float*)d_in[0];
    const int*   ei    = (const int*)d_in[1];
    const float* Wt    = (const float*)d_in[2];
    const float* bt    = (const float*)d_in[3];
    const float* gt    = (const float*)d_in[4];
    const float* bbt   = (const float*)d_in[5];
    const float* W1    = (const float*)d_in[6];
    const float* W2    = (const float*)d_in[7];
    const float* gamma = (const float*)d_in[8];
    const float* beta  = (const float*)d_in[9];
    float* out = (float*)d_out;

    char* ws = (char*)d_ws;
    float*  hA    = (float*)(ws + WS_HA);
    double* stats = (double*)(ws + WS_STATS);
    float*  ssf   = (float*)(ws + WS_SSF);
    int*    deg   = (int*)(ws + WS_DEG);
    int*    offs  = (int*)(ws + WS_OFFS);
    int*    cur   = (int*)(ws + WS_CUR);
    int*    parts = (int*)(ws + WS_PARTS);
    int*    esrc  = (int*)(ws + WS_ESRC);

    const int* srcv = ei;
    const int* dstv = ei + NED;

    // one memset covers stats + ssf + deg (contiguous)
    hipMemsetAsync(stats, 0, NCOPY * 128 * 8 + 512 + NND * 4, stream);

    const int EB4 = (NED / 4 + 255) / 256;   // 782 blocks, 4 edges/thread
    k_deg<<<EB4, 256, 0, stream>>>(dstv, deg);
    k_part<<<NSB, SCB, 0, stream>>>(deg, offs, parts);
    k_scan2<<<1, 256, 0, stream>>>(parts);
    k_apply<<<NSB, 256, 0, stream>>>(offs, parts, cur);
    k_fill<<<EB4, 256, 0, stream>>>(srcv, dstv, cur, esrc);

    const int NT2 = 391;            // 782 tiles / 2 waves per block
    const int NB  = NND / 4;        // 12500 agg blocks

    k_transform<<<NT2, 128, 0, stream>>>(x, Wt, bt, hA, stats);
    k_fin<<<1, 64, 0, stream>>>(stats, gt, bbt, ssf);

    // layer 0: hA --agg--> out --mlp(in-place)--> out
    k_agg<<<NB, 256, 0, stream>>>(hA, out, ssf, offs, esrc);
    k_mlp<<<NT2, 128, 0, stream>>>(out, stats, W1, W2);
    k_fin<<<1, 64, 0, stream>>>(stats, gamma, beta, ssf);

    // layer 1: out --agg--> hA --mlp--> hA
    k_agg<<<NB, 256, 0, stream>>>(out, hA, ssf, offs, esrc);
    k_mlp<<<NT2, 128, 0, stream>>>(hA, stats, W1 + 4096, W2 + 4096);
    k_fin<<<1, 64, 0, stream>>>(stats, gamma + 64, beta + 64, ssf);

    // layer 2: hA --agg--> out --mlp--> out
    k_agg<<<NB, 256, 0, stream>>>(hA, out, ssf, offs, esrc);
    k_mlp<<<NT2, 128, 0, stream>>>(out, stats, W1 + 8192, W2 + 8192);
    k_fin<<<1, 64, 0, stream>>>(stats, gamma + 128, beta + 128, ssf);

    k_bnout<<<(NND * NH / 4 + 255) / 256, 256, 0, stream>>>(out, ssf);
}

// Round 9
// 321.364 us; speedup vs baseline: 1.9713x; 1.0279x over previous
//
#include <hip/hip_runtime.h>

#define NND 50000
#define NED 800000
#define NF  128
#define NH  64
#define BN_EPS 1e-5
#define NCOPY 64   // stats slot-copies (contention 782/64 ~ 12 per address)
#define SCB  256   // scan chunk
#define NSB  ((NND + SCB - 1) / SCB)   // 196 scan blocks
#define XNODES (NND / 8)               // 6250 nodes per XCD slice
#define FCH  196                       // edge chunks (1024 int4 each) per XCD pass

// ---- workspace byte offsets (16B aligned) ----
#define WS_HA     0                          // float[NND*64]          12,800,000 B
#define WS_STATS  12800000                   // double[NCOPY*128]      65,536 B (self-cleaned by k_fin)
#define WS_SSF    (WS_STATS + NCOPY*128*8)   // float[128]             512 B (scale|shift)
#define WS_DEG    (WS_SSF + 512)             // int[NND]   (memset'd with stats+ssf each call)
#define WS_OFFS   (WS_DEG + NND*4)           // int[NND+4]
#define WS_CUR    (WS_OFFS + (NND+4)*4)      // int[NND]
#define WS_PARTS  (WS_CUR + NND*4)           // int[256]
#define WS_ESRC   (WS_PARTS + 256*4)         // int[NED]

// ---------------- CSR build (XCD-partitioned: lines single-XCD-owned) ----------------
// blockIdx % 8 round-robins across XCDs; XCD x owns dst range [x*XNODES, (x+1)*XNODES).
// Each block scans a 1/FCH slice of the edge list and keeps only its range ->
// deg/cur/esrc cachelines are written by ONE XCD's L2 only (kills the 16x
// write-back amplification seen in R8: WRITE_SIZE 52MB for 3.2MB of data).
__global__ __launch_bounds__(256) void k_deg(const int* __restrict__ dst,
                                             int* __restrict__ deg) {
    int xcd = blockIdx.x & 7;
    int chunk = blockIdx.x >> 3;
    int lo = xcd * XNODES;
    const int4* d4 = (const int4*)dst;
#pragma unroll
    for (int r = 0; r < 4; ++r) {
        int i = chunk * 1024 + r * 256 + threadIdx.x;
        if (i < NED / 4) {
            int4 d = d4[i];
            if ((unsigned)(d.x - lo) < XNODES) atomicAdd(&deg[d.x], 1);
            if ((unsigned)(d.y - lo) < XNODES) atomicAdd(&deg[d.y], 1);
            if ((unsigned)(d.z - lo) < XNODES) atomicAdd(&deg[d.z], 1);
            if ((unsigned)(d.w - lo) < XNODES) atomicAdd(&deg[d.w], 1);
        }
    }
}

__global__ __launch_bounds__(256) void k_fill(const int* __restrict__ src,
                                              const int* __restrict__ dst,
                                              int* __restrict__ cur,
                                              int* __restrict__ esrc) {
    int xcd = blockIdx.x & 7;
    int chunk = blockIdx.x >> 3;
    int lo = xcd * XNODES;
    const int4* d4 = (const int4*)dst;
#pragma unroll
    for (int r = 0; r < 4; ++r) {
        int i = chunk * 1024 + r * 256 + threadIdx.x;
        if (i < NED / 4) {
            int4 d = d4[i];
            int e = i * 4;
            if ((unsigned)(d.x - lo) < XNODES) esrc[atomicAdd(&cur[d.x], 1)] = src[e];
            if ((unsigned)(d.y - lo) < XNODES) esrc[atomicAdd(&cur[d.y], 1)] = src[e + 1];
            if ((unsigned)(d.z - lo) < XNODES) esrc[atomicAdd(&cur[d.z], 1)] = src[e + 2];
            if ((unsigned)(d.w - lo) < XNODES) esrc[atomicAdd(&cur[d.w], 1)] = src[e + 3];
        }
    }
}

// pass 1: per-256-chunk exclusive scan into offs, chunk totals into parts
__global__ __launch_bounds__(SCB) void k_part(const int* __restrict__ deg,
                                              int* __restrict__ offs,
                                              int* __restrict__ parts) {
    __shared__ int sd[SCB];
    int t = threadIdx.x;
    int i = blockIdx.x * SCB + t;
    int v = (i < NND) ? deg[i] : 0;
    sd[t] = v;
    __syncthreads();
#pragma unroll
    for (int off = 1; off < SCB; off <<= 1) {
        int u = (t >= off) ? sd[t - off] : 0;
        __syncthreads();
        sd[t] += u;
        __syncthreads();
    }
    if (i < NND) offs[i] = sd[t] - v;                 // block-local exclusive
    if (t == SCB - 1) parts[blockIdx.x] = sd[t];
}

// pass 2: exclusive scan of the 196 partials (single tiny block)
__global__ __launch_bounds__(256) void k_scan2(int* __restrict__ parts) {
    __shared__ int sd[256];
    int t = threadIdx.x;
    int v = (t < NSB) ? parts[t] : 0;
    sd[t] = v;
    __syncthreads();
#pragma unroll
    for (int off = 1; off < 256; off <<= 1) {
        int u = (t >= off) ? sd[t - off] : 0;
        __syncthreads();
        sd[t] += u;
        __syncthreads();
    }
    if (t < NSB) parts[t] = sd[t] - v;                // exclusive
}

// pass 3: add block offsets; write cur=offs; offs[NND]=NED (constant)
__global__ __launch_bounds__(256) void k_apply(int* __restrict__ offs,
                                               const int* __restrict__ parts,
                                               int* __restrict__ cur) {
    int i = blockIdx.x * 256 + threadIdx.x;
    if (i < NND) {
        int o = offs[i] + parts[i >> 8];
        offs[i] = o;
        cur[i] = o;
    }
    if (i == NND) offs[NND] = NED;
}

// ---------------- BN finalize: reduce slot-copies -> float sc/sh; self-clean ----------------
__global__ void k_fin(double* __restrict__ st,
                      const float* __restrict__ g, const float* __restrict__ b,
                      float* __restrict__ ssout) {
    int c = threadIdx.x;   // 64 threads
    double sum = 0.0, ssq = 0.0;
    for (int cp = 0; cp < NCOPY; ++cp) {
        sum += st[cp * 128 + c];
        ssq += st[cp * 128 + 64 + c];
    }
    for (int cp = 0; cp < NCOPY; ++cp) {
        st[cp * 128 + c] = 0.0;
        st[cp * 128 + 64 + c] = 0.0;
    }
    double mu  = sum / (double)NND;
    double var = ssq / (double)NND - mu * mu;
    if (var < 0.0) var = 0.0;
    double rs = 1.0 / sqrt(var + BN_EPS);
    double sc = (double)g[c] * rs;
    ssout[c]      = (float)sc;
    ssout[64 + c] = (float)((double)b[c] - mu * sc);
}

// ---------------- input transform: wave-per-tile 8x8 GEMM, K=128 chunked ----------------
__global__ __launch_bounds__(128) void k_transform(const float* __restrict__ x,
                                                   const float* __restrict__ Wt,
                                                   const float* __restrict__ bt,
                                                   float* __restrict__ outraw,
                                                   double* __restrict__ stats) {
    __shared__ __align__(16) float Wl[NF * NH];        // 32 KB
    __shared__ __align__(16) float sTbuf[2 * 64 * 68]; // 2 x 17.4 KB
    int tid  = threadIdx.x;
    int wave = tid >> 6, lane = tid & 63;
    int ti = lane & 7, tj = lane >> 3;
    int tile = blockIdx.x * 2 + wave;                  // 0..781
    int base = tile * 64;
    float* sTw = &sTbuf[wave * 64 * 68];
    const float4* x4 = (const float4*)x;

#pragma unroll
    for (int r = 0; r < 16; ++r) {
        int i4 = r * 128 + tid;
        ((float4*)Wl)[i4] = ((const float4*)Wt)[i4];
    }

    float acc[8][8];
#pragma unroll
    for (int i = 0; i < 8; ++i)
#pragma unroll
        for (int j = 0; j < 8; ++j) acc[i][j] = 0.f;

    for (int ch = 0; ch < 2; ++ch) {
        __syncthreads();
#pragma unroll
        for (int s = 0; s < 16; ++s) {
            int flat = s * 64 + lane;
            int nl = flat >> 4, q = flat & 15;
            float4 v = {0.f, 0.f, 0.f, 0.f};
            if (base + nl < NND) v = x4[(size_t)(base + nl) * 32 + ch * 16 + q];
            sTw[(q * 4 + 0) * 68 + nl] = v.x;
            sTw[(q * 4 + 1) * 68 + nl] = v.y;
            sTw[(q * 4 + 2) * 68 + nl] = v.z;
            sTw[(q * 4 + 3) * 68 + nl] = v.w;
        }
        __syncthreads();
#pragma unroll 2
        for (int k = 0; k < 64; ++k) {
            const float* ap = &sTw[k * 68 + ti * 8];
            float4 alo = *(const float4*)ap;
            float4 ahi = *(const float4*)(ap + 4);
            const float* wp = &Wl[(ch * 64 + k) * NH + tj * 8];
            float4 wlo = *(const float4*)wp;
            float4 whi = *(const float4*)(wp + 4);
            float a8[8] = {alo.x, alo.y, alo.z, alo.w, ahi.x, ahi.y, ahi.z, ahi.w};
            float w8[8] = {wlo.x, wlo.y, wlo.z, wlo.w, whi.x, whi.y, whi.z, whi.w};
#pragma unroll
            for (int i = 0; i < 8; ++i)
#pragma unroll
                for (int j = 0; j < 8; ++j) acc[i][j] += a8[i] * w8[j];
        }
    }

    float b8[8];
    *(float4*)&b8[0] = ((const float4*)bt)[tj * 2];
    *(float4*)&b8[4] = ((const float4*)bt)[tj * 2 + 1];

    float s8[8], q8[8];
#pragma unroll
    for (int j = 0; j < 8; ++j) { s8[j] = 0.f; q8[j] = 0.f; }
#pragma unroll
    for (int i = 0; i < 8; ++i) {
        int n = base + ti * 8 + i;
        if (n < NND) {
            float o[8];
#pragma unroll
            for (int j = 0; j < 8; ++j) {
                o[j] = acc[i][j] + b8[j];
                s8[j] += o[j];
                q8[j] += o[j] * o[j];
            }
            *(float4*)&outraw[(size_t)n * NH + tj * 8]     = *(float4*)&o[0];
            *(float4*)&outraw[(size_t)n * NH + tj * 8 + 4] = *(float4*)&o[4];
        }
    }
#pragma unroll
    for (int m = 1; m < 8; m <<= 1) {
#pragma unroll
        for (int j = 0; j < 8; ++j) {
            s8[j] += __shfl_xor(s8[j], m);
            q8[j] += __shfl_xor(q8[j], m);
        }
    }
    if (ti == 0) {
        int slot = (tile & (NCOPY - 1)) * 128 + tj * 8;
#pragma unroll
        for (int j = 0; j < 8; ++j) {
            atomicAdd(&stats[slot + j], (double)s8[j]);
            atomicAdd(&stats[slot + 64 + j], (double)q8[j]);
        }
    }
}

// ---------------- aggregation: wave-per-node, float4 gather, BN via precomputed sc/sh ----------------
__global__ __launch_bounds__(256) void k_agg(const float* __restrict__ inraw,
                                             float* __restrict__ aggout,
                                             const float* __restrict__ ss,
                                             const int* __restrict__ offs,
                                             const int* __restrict__ esrc) {
    int tid  = threadIdx.x;
    int lane = tid & 63;
    int wv   = tid >> 6;
    int n = blockIdx.x * 4 + wv;
    int q = lane & 15;
    int r = lane >> 4;
    const float4* in4 = (const float4*)inraw;

    int e0 = offs[n], e1 = offs[n + 1];
    int deg = e1 - e0;

    float4 self = make_float4(0.f, 0.f, 0.f, 0.f);
    if (r == 0) self = in4[(size_t)n * 16 + q];

    float ax = 0.f, ay = 0.f, az = 0.f, aw = 0.f;
    for (int bb = e0; bb < e1; bb += 64) {
        int m = e1 - bb; if (m > 64) m = 64;
        int idx = (lane < m) ? esrc[bb + lane] : 0;
        int t = 0;
        for (; t + 16 <= m; t += 16) {
            int j0 = __shfl(idx, t + r);
            int j1 = __shfl(idx, t + 4 + r);
            int j2 = __shfl(idx, t + 8 + r);
            int j3 = __shfl(idx, t + 12 + r);
            float4 v0 = in4[(size_t)j0 * 16 + q];
            float4 v1 = in4[(size_t)j1 * 16 + q];
            float4 v2 = in4[(size_t)j2 * 16 + q];
            float4 v3 = in4[(size_t)j3 * 16 + q];
            ax += (v0.x + v1.x) + (v2.x + v3.x);
            ay += (v0.y + v1.y) + (v2.y + v3.y);
            az += (v0.z + v1.z) + (v2.z + v3.z);
            aw += (v0.w + v1.w) + (v2.w + v3.w);
        }
        for (; t < m; t += 4) {
            int e = t + r;
            int j = __shfl(idx, e & 63);
            if (e < m) {
                float4 v = in4[(size_t)j * 16 + q];
                ax += v.x; ay += v.y; az += v.z; aw += v.w;
            }
        }
    }

    ax += __shfl_xor(ax, 16); ay += __shfl_xor(ay, 16);
    az += __shfl_xor(az, 16); aw += __shfl_xor(aw, 16);
    ax += __shfl_xor(ax, 32); ay += __shfl_xor(ay, 32);
    az += __shfl_xor(az, 32); aw += __shfl_xor(aw, 32);

    if (r == 0) {
        float4 sc4 = ((const float4*)ss)[q];
        float4 sh4 = ((const float4*)(ss + 64))[q];
        float dn = (float)(deg + 1);
        float4 res;
        res.x = sc4.x * (ax + self.x) + dn * sh4.x;
        res.y = sc4.y * (ay + self.y) + dn * sh4.y;
        res.z = sc4.z * (az + self.z) + dn * sh4.z;
        res.w = sc4.w * (aw + self.w) + dn * sh4.w;
        ((float4*)aggout)[(size_t)n * 16 + q] = res;
    }
}

// ---------------- MLP: wave-per-tile 8x8 GEMM x2, relu, in-place, + stats partials ----------------
__global__ __launch_bounds__(128) void k_mlp(float* __restrict__ h,
                                             double* __restrict__ statsout,
                                             const float* __restrict__ W1,
                                             const float* __restrict__ W2) {
    __shared__ __align__(16) float W1l[NH * NH];       // 16 KB
    __shared__ __align__(16) float W2l[NH * NH];       // 16 KB
    __shared__ __align__(16) float sTbuf[2 * 64 * 68]; // 2 x 17.4 KB
    int tid  = threadIdx.x;
    int wave = tid >> 6, lane = tid & 63;
    int ti = lane & 7, tj = lane >> 3;
    int tile = blockIdx.x * 2 + wave;
    int base = tile * 64;
    float* sTw = &sTbuf[wave * 64 * 68];
    const float4* h4 = (const float4*)h;

#pragma unroll
    for (int r = 0; r < 8; ++r) {
        int i4 = r * 128 + tid;
        ((float4*)W1l)[i4] = ((const float4*)W1)[i4];
        ((float4*)W2l)[i4] = ((const float4*)W2)[i4];
    }
#pragma unroll
    for (int s = 0; s < 16; ++s) {
        int flat = s * 64 + lane;
        int nl = flat >> 4, q = flat & 15;
        float4 v = {0.f, 0.f, 0.f, 0.f};
        if (base + nl < NND) v = h4[(size_t)(base + nl) * 16 + q];
        sTw[(q * 4 + 0) * 68 + nl] = v.x;
        sTw[(q * 4 + 1) * 68 + nl] = v.y;
        sTw[(q * 4 + 2) * 68 + nl] = v.z;
        sTw[(q * 4 + 3) * 68 + nl] = v.w;
    }
    __syncthreads();

    float acc[8][8];
#pragma unroll
    for (int i = 0; i < 8; ++i)
#pragma unroll
        for (int j = 0; j < 8; ++j) acc[i][j] = 0.f;
#pragma unroll 2
    for (int k = 0; k < 64; ++k) {
        const float* ap = &sTw[k * 68 + ti * 8];
        float4 alo = *(const float4*)ap;
        float4 ahi = *(const float4*)(ap + 4);
        const float* wp = &W1l[k * NH + tj * 8];
        float4 wlo = *(const float4*)wp;
        float4 whi = *(const float4*)(wp + 4);
        float a8[8] = {alo.x, alo.y, alo.z, alo.w, ahi.x, ahi.y, ahi.z, ahi.w};
        float w8[8] = {wlo.x, wlo.y, wlo.z, wlo.w, whi.x, whi.y, whi.z, whi.w};
#pragma unroll
        for (int i = 0; i < 8; ++i)
#pragma unroll
            for (int j = 0; j < 8; ++j) acc[i][j] += a8[i] * w8[j];
    }
#pragma unroll
    for (int i = 0; i < 8; ++i)
#pragma unroll
        for (int j = 0; j < 8; ++j) acc[i][j] = fmaxf(acc[i][j], 0.f);

    __syncthreads();
#pragma unroll
    for (int j = 0; j < 8; ++j) {
        float* p = &sTw[(tj * 8 + j) * 68 + ti * 8];
        float4 lo = {acc[0][j], acc[1][j], acc[2][j], acc[3][j]};
        float4 hi = {acc[4][j], acc[5][j], acc[6][j], acc[7][j]};
        *(float4*)p = lo;
        *(float4*)(p + 4) = hi;
    }
    __syncthreads();

    float a2[8][8];
#pragma unroll
    for (int i = 0; i < 8; ++i)
#pragma unroll
        for (int j = 0; j < 8; ++j) a2[i][j] = 0.f;
#pragma unroll 2
    for (int k = 0; k < 64; ++k) {
        const float* ap = &sTw[k * 68 + ti * 8];
        float4 alo = *(const float4*)ap;
        float4 ahi = *(const float4*)(ap + 4);
        const float* wp = &W2l[k * NH + tj * 8];
        float4 wlo = *(const float4*)wp;
        float4 whi = *(const float4*)(wp + 4);
        float a8[8] = {alo.x, alo.y, alo.z, alo.w, ahi.x, ahi.y, ahi.z, ahi.w};
        float w8[8] = {wlo.x, wlo.y, wlo.z, wlo.w, whi.x, whi.y, whi.z, whi.w};
#pragma unroll
        for (int i = 0; i < 8; ++i)
#pragma unroll
            for (int j = 0; j < 8; ++j) a2[i][j] += a8[i] * w8[j];
    }

    float s8[8], q8[8];
#pragma unroll
    for (int j = 0; j < 8; ++j) { s8[j] = 0.f; q8[j] = 0.f; }
#pragma unroll
    for (int i = 0; i < 8; ++i) {
        int n = base + ti * 8 + i;
        if (n < NND) {
            float o[8];
#pragma unroll
            for (int j = 0; j < 8; ++j) {
                o[j] = fmaxf(a2[i][j], 0.f);
                s8[j] += o[j];
                q8[j] += o[j] * o[j];
            }
            *(float4*)&h[(size_t)n * NH + tj * 8]     = *(float4*)&o[0];
            *(float4*)&h[(size_t)n * NH + tj * 8 + 4] = *(float4*)&o[4];
        }
    }
#pragma unroll
    for (int m = 1; m < 8; m <<= 1) {
#pragma unroll
        for (int j = 0; j < 8; ++j) {
            s8[j] += __shfl_xor(s8[j], m);
            q8[j] += __shfl_xor(q8[j], m);
        }
    }
    if (ti == 0) {
        int slot = (tile & (NCOPY - 1)) * 128 + tj * 8;
#pragma unroll
        for (int j = 0; j < 8; ++j) {
            atomicAdd(&statsout[slot + j], (double)s8[j]);
            atomicAdd(&statsout[slot + 64 + j], (double)q8[j]);
        }
    }
}

// ---------------- final BN apply, in-place, sc/sh precomputed ----------------
__global__ void k_bnout(float* __restrict__ h, const float* __restrict__ ss) {
    int i4 = blockIdx.x * 256 + threadIdx.x;
    if (i4 < NND * NH / 4) {
        int cg = i4 & 15;
        float4 v   = ((float4*)h)[i4];
        float4 scv = ((const float4*)ss)[cg];
        float4 shv = ((const float4*)(ss + 64))[cg];
        v.x = v.x * scv.x + shv.x;
        v.y = v.y * scv.y + shv.y;
        v.z = v.z * scv.z + shv.z;
        v.w = v.w * scv.w + shv.w;
        ((float4*)h)[i4] = v;
    }
}

extern "C" void kernel_launch(void* const* d_in, const int* in_sizes, int n_in,
                              void* d_out, int out_size, void* d_ws, size_t ws_size,
                              hipStream_t stream) {
    const float* x     = (const float*)d_in[0];
    const int*   ei    = (const int*)d_in[1];
    const float* Wt    = (const float*)d_in[2];
    const float* bt    = (const float*)d_in[3];
    const float* gt    = (const float*)d_in[4];
    const float* bbt   = (const float*)d_in[5];
    const float* W1    = (const float*)d_in[6];
    const float* W2    = (const float*)d_in[7];
    const float* gamma = (const float*)d_in[8];
    const float* beta  = (const float*)d_in[9];
    float* out = (float*)d_out;

    char* ws = (char*)d_ws;
    float*  hA    = (float*)(ws + WS_HA);
    double* stats = (double*)(ws + WS_STATS);
    float*  ssf   = (float*)(ws + WS_SSF);
    int*    deg   = (int*)(ws + WS_DEG);
    int*    offs  = (int*)(ws + WS_OFFS);
    int*    cur   = (int*)(ws + WS_CUR);
    int*    parts = (int*)(ws + WS_PARTS);
    int*    esrc  = (int*)(ws + WS_ESRC);

    const int* srcv = ei;
    const int* dstv = ei + NED;

    // one memset covers stats + ssf + deg (contiguous)
    hipMemsetAsync(stats, 0, NCOPY * 128 * 8 + 512 + NND * 4, stream);

    const int PGRID = FCH * 8;   // 1568 blocks: 8 XCD slices x 196 edge chunks
    k_deg<<<PGRID, 256, 0, stream>>>(dstv, deg);
    k_part<<<NSB, SCB, 0, stream>>>(deg, offs, parts);
    k_scan2<<<1, 256, 0, stream>>>(parts);
    k_apply<<<NSB, 256, 0, stream>>>(offs, parts, cur);
    k_fill<<<PGRID, 256, 0, stream>>>(srcv, dstv, cur, esrc);

    const int NT2 = 391;            // 782 tiles / 2 waves per block
    const int NB  = NND / 4;        // 12500 agg blocks

    k_transform<<<NT2, 128, 0, stream>>>(x, Wt, bt, hA, stats);
    k_fin<<<1, 64, 0, stream>>>(stats, gt, bbt, ssf);

    // layer 0: hA --agg--> out --mlp(in-place)--> out
    k_agg<<<NB, 256, 0, stream>>>(hA, out, ssf, offs, esrc);
    k_mlp<<<NT2, 128, 0, stream>>>(out, stats, W1, W2);
    k_fin<<<1, 64, 0, stream>>>(stats, gamma, beta, ssf);

    // layer 1: out --agg--> hA --mlp--> hA
    k_agg<<<NB, 256, 0, stream>>>(out, hA, ssf, offs, esrc);
    k_mlp<<<NT2, 128, 0, stream>>>(hA, stats, W1 + 4096, W2 + 4096);
    k_fin<<<1, 64, 0, stream>>>(stats, gamma + 64, beta + 64, ssf);

    // layer 2: hA --agg--> out --mlp--> out
    k_agg<<<NB, 256, 0, stream>>>(hA, out, ssf, offs, esrc);
    k_mlp<<<NT2, 128, 0, stream>>>(out, stats, W1 + 8192, W2 + 8192);
    k_fin<<<1, 64, 0, stream>>>(stats, gamma + 128, beta + 128, ssf);

    k_bnout<<<(NND * NH / 4 + 255) / 256, 256, 0, stream>>>(out, ssf);
}